// Round 11
// baseline (211.904 us; speedup 1.0000x reference)
//
#include <hip/hip_runtime.h>
#include <stdint.h>

typedef unsigned short u16;
typedef __attribute__((ext_vector_type(8))) short bf16x8;   // 8 bf16 = 4 VGPRs (MFMA A/B frag)
typedef __attribute__((ext_vector_type(4))) float f32x4;    // MFMA C/D frag
typedef __attribute__((ext_vector_type(4))) unsigned int u32x4;
typedef __attribute__((ext_vector_type(2))) unsigned int u32x2;
typedef __attribute__((ext_vector_type(4))) unsigned short u16x4;

#define QSCALE 0.18033688011112042f   // 0.125 * log2(e): softmax scale folded into Q, exp via exp2

typedef __attribute__((address_space(1))) const void gvoid;
typedef __attribute__((address_space(3))) void svoid;

__device__ __forceinline__ void cp16(const u16* g, u16* l) {
    // async global->LDS, 16B/lane; LDS dst = wave-uniform base + lane*16
    __builtin_amdgcn_global_load_lds((gvoid*)g, (svoid*)l, 16, 0, 0);
}

__device__ __forceinline__ u16 f2bf(float f) {
    uint32_t u = __float_as_uint(f);
    u += 0x7fff + ((u >> 16) & 1);   // round-to-nearest-even
    return (u16)(u >> 16);
}

__device__ __forceinline__ float bf2f(u16 u) {
    return __uint_as_float(((uint32_t)u) << 16);
}

// pack bf16(lo), bf16(hi) into one u32: round-half-up — 2 adds + 1 perm per 2 elems
__device__ __forceinline__ uint32_t pack_bf2(float lo, float hi) {
    uint32_t a = __float_as_uint(lo) + 0x8000u;
    uint32_t b = __float_as_uint(hi) + 0x8000u;
    return __builtin_amdgcn_perm(b, a, 0x07060302);
}

// ---------------------------------------------------------------- fused pre-pass:
// blocks [0,4096): LayerNorm token t -> XN bf16; blocks [4096,8192): weight fp32->bf16 cast
__global__ __launch_bounds__(256) void k_pre(const float* __restrict__ X,
                                             const float* __restrict__ gam,
                                             const float* __restrict__ bet,
                                             u16* __restrict__ XN,
                                             const float* __restrict__ Wqkv, u16* __restrict__ Wq,
                                             const float* __restrict__ Wout, u16* __restrict__ Wo) {
    __shared__ float red[8];
    const int bid = blockIdx.x;
    if (bid < 4096) {
        int t = bid;
        const float4* xp = (const float4*)(X + (size_t)t * 1024);
        float4 x = xp[threadIdx.x];
        float s  = x.x + x.y + x.z + x.w;
        float s2 = x.x*x.x + x.y*x.y + x.z*x.z + x.w*x.w;
        #pragma unroll
        for (int off = 1; off < 64; off <<= 1) {
            s  += __shfl_xor(s,  off, 64);
            s2 += __shfl_xor(s2, off, 64);
        }
        int lane = threadIdx.x & 63, w = threadIdx.x >> 6;
        if (lane == 0) { red[w] = s; red[w + 4] = s2; }
        __syncthreads();
        s  = red[0] + red[1] + red[2] + red[3];
        s2 = red[4] + red[5] + red[6] + red[7];
        float mu  = s * (1.0f / 1024.0f);
        float var = s2 * (1.0f / 1024.0f) - mu * mu;
        float rin = rsqrtf(var + 1e-5f);
        float4 g = ((const float4*)gam)[threadIdx.x];
        float4 b = ((const float4*)bet)[threadIdx.x];
        u16x4 o;
        o.x = f2bf((x.x - mu) * rin * g.x + b.x);
        o.y = f2bf((x.y - mu) * rin * g.y + b.y);
        o.z = f2bf((x.z - mu) * rin * g.z + b.z);
        o.w = f2bf((x.w - mu) * rin * g.w + b.w);
        *(u16x4*)(XN + (size_t)t * 1024 + threadIdx.x * 4) = o;
    } else {
        int i = (bid - 4096) * 256 + threadIdx.x;      // over 1048576 float4s total
        const float* src; u16* dst;
        if (i < 786432) { src = Wqkv; dst = Wq; }
        else            { i -= 786432; src = Wout; dst = Wo; }
        float4 v = ((const float4*)src)[i];
        u16x4 o;
        o.x = f2bf(v.x); o.y = f2bf(v.y); o.z = f2bf(v.z); o.w = f2bf(v.w);
        ((u16x4*)dst)[i] = o;
    }
}

// ---------------------------------------------------------------- shared GEMM mainloop
// m97-style + XOR-granule swizzle: LDS granule (row,cg) holds global col-granule cg^(row&7).
__device__ __forceinline__ void gemm_bt_tile(const u16* __restrict__ A, const u16* __restrict__ Bm,
                                             int m0, int n0, u16* As, u16* Bs, f32x4 acc[4][4]) {
    const int tid = threadIdx.x;
    const int lane = tid & 63;
    const int wv = tid >> 6;
    const int qi = lane & 15, g = lane >> 4, swz = qi & 7;
    const int wr = (wv >> 1) * 64, wc = (wv & 1) * 64;
    #pragma unroll
    for (int mi = 0; mi < 4; mi++)
        #pragma unroll
        for (int ni = 0; ni < 4; ni++) acc[mi][ni] = (f32x4){0.f, 0.f, 0.f, 0.f};

    const int row_in = tid >> 3;
    const int cs = (tid & 7) ^ (row_in & 7);       // swizzled source col-granule (i*32 preserves row&7)
    for (int k0 = 0; k0 < 1024; k0 += 64) {
        __syncthreads();
        #pragma unroll
        for (int i = 0; i < 4; i++) {
            int row = i * 32 + row_in;
            cp16(A  + (size_t)(m0 + row) * 1024 + k0 + cs * 8, As + (i * 256 + wv * 64) * 8);
            cp16(Bm + (size_t)(n0 + row) * 1024 + k0 + cs * 8, Bs + (i * 256 + wv * 64) * 8);
        }
        __syncthreads();
        #pragma unroll
        for (int ks = 0; ks < 2; ks++) {
            bf16x8 af[4], bf[4];
            #pragma unroll
            for (int mi = 0; mi < 4; mi++)
                af[mi] = *(const bf16x8*)(As + (wr + mi * 16 + qi) * 64 + ((ks * 4 + g) ^ swz) * 8);
            #pragma unroll
            for (int ni = 0; ni < 4; ni++)
                bf[ni] = *(const bf16x8*)(Bs + (wc + ni * 16 + qi) * 64 + ((ks * 4 + g) ^ swz) * 8);
            #pragma unroll
            for (int mi = 0; mi < 4; mi++)
                #pragma unroll
                for (int ni = 0; ni < 4; ni++)
                    acc[mi][ni] = __builtin_amdgcn_mfma_f32_16x16x32_bf16(af[mi], bf[ni], acc[mi][ni], 0, 0, 0);
        }
    }
}

// ---------------------------------------------------------------- QKV GEMM + bias + scatter
__global__ __launch_bounds__(256) void k_qkv(const u16* __restrict__ XN, const u16* __restrict__ Wq,
                                             const float* __restrict__ bqkv,
                                             u16* __restrict__ Q, u16* __restrict__ K,
                                             u16* __restrict__ Vt) {
    __shared__ __align__(16) u16 SMEM[17408];      // union: As+Bs (16384) | 4 x T(64x68=4352)
    u16* As = SMEM;
    u16* Bs = SMEM + 8192;
    f32x4 acc[4][4];
    const int m0 = blockIdx.y * 128, n0 = blockIdx.x * 128;
    gemm_bt_tile(XN, Wq, m0, n0, As, Bs, acc);
    const int lane = threadIdx.x & 63, wid = threadIdx.x >> 6;
    const int g = lane >> 4, qi = lane & 15;
    const int wr = (wid >> 1) * 64, wc = (wid & 1) * 64;
    if (n0 < 2048) {
        const int which = n0 >> 10;                // 0 = Q, 1 = K (block-uniform)
        u16* base = which ? K : Q;
        const float scale = which ? 1.0f : QSCALE;
        #pragma unroll
        for (int mi = 0; mi < 4; mi++)
            #pragma unroll
            for (int ni = 0; ni < 4; ni++)
                #pragma unroll
                for (int i = 0; i < 4; i++) {
                    int m = m0 + wr + mi * 16 + (g * 4 + i);
                    int n = n0 + wc + ni * 16 + qi;
                    float v = (acc[mi][ni][i] + bqkv[n]) * scale;
                    int b = m >> 11, s = m & 2047;
                    int hh = (n >> 6) & 15, d = n & 63;
                    base[((size_t)(b * 16 + hh) * 2048 + s) * 64 + d] = f2bf(v);
                }
    } else {
        __syncthreads();                           // all waves done reading As/Bs
        u16* Tw = SMEM + wid * 4352;               // per-wave 64x68 (stride 68: 8B-aligned rows)
        #pragma unroll
        for (int mi = 0; mi < 4; mi++)
            #pragma unroll
            for (int ni = 0; ni < 4; ni++) {
                int n = n0 + wc + ni * 16 + qi;
                float bq = bqkv[n];
                u16x4 pk;
                pk.x = f2bf(acc[mi][ni][0] + bq);
                pk.y = f2bf(acc[mi][ni][1] + bq);
                pk.z = f2bf(acc[mi][ni][2] + bq);
                pk.w = f2bf(acc[mi][ni][3] + bq);
                *(u16x4*)(Tw + (ni * 16 + qi) * 68 + mi * 16 + g * 4) = pk;
            }
        const int head = (n0 + wc - 2048) >> 6;
        const int b = m0 >> 11;
        const int s0 = (m0 + wr) & 2047;           // s within the batch (R7 fix)
        u16* vrow = Vt + (size_t)(b * 16 + head) * 64 * 2048 + s0 + qi * 4;
        #pragma unroll
        for (int dd = 0; dd < 16; dd++) {
            int d = dd * 4 + g;
            u16x4 val = *(const u16x4*)(Tw + d * 68 + qi * 4);
            *(u16x4*)(vrow + (size_t)d * 2048) = val;
        }
    }
}

// ---------------------------------------------------------------- attention v9: split-K
// 1024 blocks = 32 bh x 16 q-tiles(128) x 2 key-halves(1024 keys). R10 inner loop
// (4 waves, F=2 Q-frags) verbatim over 16 kt steps. Writes UN-normalized partial O (bf16)
// + partial row-sum L (f32); k_red combines. Restores 12 waves/CU (R10 had 8) while
// keeping F=2's halved LDS traffic — waves = 4096/F was the R10 regression cause.
__global__ __launch_bounds__(256) void k_attn(const u16* __restrict__ Q, const u16* __restrict__ K,
                                              const u16* __restrict__ Vt,
                                              u16* __restrict__ OP0, u16* __restrict__ OP1,
                                              float* __restrict__ LS) {
    __shared__ __align__(16) u16 Ks[2][64 * 64];   // elem(key r, d c) at r*64 + ((c>>3)^(r&7))*8 + (c&7)
    __shared__ __align__(16) u16 Vs[2][64 * 64];   // elem(d r, key c) same swizzle
    __shared__ __align__(16) u16 Ps[4][32 * 64];   // per-wave 32q x 64k, row q, same swizzle
    const int id = blockIdx.x;
    const int bh = (id & 7) * 4 + ((id >> 3) & 3); // id%8 constant per bh -> same XCD
    const int q0 = ((id >> 5) & 15) * 128;
    const int half = id >> 9;                      // key half: [0,1024) or [1024,2048)
    const int lane = threadIdx.x & 63, w = threadIdx.x >> 6;   // w in 0..3
    const int g = lane >> 4, qi = lane & 15, swz = qi & 7;
    const u16* Qp = Q  + (size_t)bh * (2048 * 64);
    const u16* Kp = K  + (size_t)bh * (2048 * 64);
    const u16* Vp = Vt + (size_t)bh * (64 * 2048);
    u16* Pw = Ps[w];

    // staging: 256 lanes x 16B = half a 64x64 tile per cp16 -> 2 instrs/tile
    const int r0 = threadIdx.x >> 3;               // tile row 0..31 (i=0), +32 (i=1)
    const int cs = (threadIdx.x & 7) ^ (r0 & 7);   // swizzled col-granule (+32 preserves &7)
    const u16* kg0 = Kp + (size_t)(half * 1024 + r0) * 64 + cs * 8;
    const u16* kg1 = kg0 + 32 * 64;
    const u16* vg0 = Vp + (size_t)r0 * 2048 + half * 1024 + cs * 8;
    const u16* vg1 = vg0 + 32 * 2048;

    bf16x8 bq[2][2];                               // [frag f][ks]
    #pragma unroll
    for (int f = 0; f < 2; f++) {
        const u16* qb = Qp + (size_t)(q0 + w * 32 + f * 16 + qi) * 64 + g * 8;
        bq[f][0] = *(const bf16x8*)(qb);
        bq[f][1] = *(const bf16x8*)(qb + 32);
    }
    float lsum0 = 0.f, lsum1 = 0.f;
    f32x4 od[2][4];
    #pragma unroll
    for (int f = 0; f < 2; f++)
        #pragma unroll
        for (int nt = 0; nt < 4; nt++) od[f][nt] = (f32x4){0.f, 0.f, 0.f, 0.f};

    // preload tile 0 -> buf 0
    cp16(kg0, Ks[0] + w * 512);
    cp16(kg1, Ks[0] + 2048 + w * 512);
    cp16(vg0, Vs[0] + w * 512);
    cp16(vg1, Vs[0] + 2048 + w * 512);

    #define ATTN_STEP(KT, CKS, CVS, PKS, PVS)                                                    \
    {                                                                                            \
        const int kt_ = (KT);                                                                    \
        __syncthreads();                                                                         \
        if (kt_ < 15) {                                                                          \
            cp16(kg0 + 4096, (PKS) + w * 512);                                                   \
            cp16(kg1 + 4096, (PKS) + 2048 + w * 512);                                            \
            cp16(vg0 + 64,   (PVS) + w * 512);                                                   \
            cp16(vg1 + 64,   (PVS) + 2048 + w * 512);                                            \
        }                                                                                        \
        const u16* ksp = (CKS);                                                                  \
        const u16* vsp = (CVS);                                                                  \
        f32x4 sv[2][4];                                                                          \
        _Pragma("unroll")                                                                        \
        for (int f = 0; f < 2; f++)                                                              \
            _Pragma("unroll")                                                                    \
            for (int nt = 0; nt < 4; nt++) sv[f][nt] = (f32x4){0.f, 0.f, 0.f, 0.f};              \
        _Pragma("unroll")                                                                        \
        for (int ks = 0; ks < 2; ks++)                                                           \
            _Pragma("unroll")                                                                    \
            for (int nt = 0; nt < 4; nt++) {                                                     \
                bf16x8 ak = *(const bf16x8*)(ksp + (nt * 16 + qi) * 64 + ((ks * 4 + g) ^ swz) * 8); \
                sv[0][nt] = __builtin_amdgcn_mfma_f32_16x16x32_bf16(ak, bq[0][ks], sv[0][nt], 0, 0, 0); \
                sv[1][nt] = __builtin_amdgcn_mfma_f32_16x16x32_bf16(ak, bq[1][ks], sv[1][nt], 0, 0, 0); \
            }                                                                                    \
        _Pragma("unroll")                                                                        \
        for (int f = 0; f < 2; f++)                                                              \
            _Pragma("unroll")                                                                    \
            for (int nt = 0; nt < 2; nt++) {                                                     \
                float e0 = __builtin_amdgcn_exp2f(sv[f][nt][0]);                                 \
                float e1 = __builtin_amdgcn_exp2f(sv[f][nt][1]);                                 \
                float e2 = __builtin_amdgcn_exp2f(sv[f][nt][2]);                                 \
                float e3 = __builtin_amdgcn_exp2f(sv[f][nt][3]);                                 \
                if (f == 0) lsum0 += (e0 + e1) + (e2 + e3); else lsum1 += (e0 + e1) + (e2 + e3); \
                u32x2 pk = {pack_bf2(e0, e1), pack_bf2(e2, e3)};                                 \
                *(u32x2*)(Pw + (f * 16 + qi) * 64 + ((2 * nt + (g >> 1)) ^ swz) * 8 + (g & 1) * 4) = pk; \
            }                                                                                    \
        {                                                                                        \
            bf16x8 bp0 = *(const bf16x8*)(Pw + qi * 64 + (g ^ swz) * 8);                         \
            bf16x8 bp1 = *(const bf16x8*)(Pw + (16 + qi) * 64 + (g ^ swz) * 8);                  \
            _Pragma("unroll")                                                                    \
            for (int nt = 0; nt < 4; nt++) {                                                     \
                bf16x8 av = *(const bf16x8*)(vsp + (nt * 16 + qi) * 64 + (g ^ swz) * 8);         \
                od[0][nt] = __builtin_amdgcn_mfma_f32_16x16x32_bf16(av, bp0, od[0][nt], 0, 0, 0); \
                od[1][nt] = __builtin_amdgcn_mfma_f32_16x16x32_bf16(av, bp1, od[1][nt], 0, 0, 0); \
            }                                                                                    \
        }                                                                                        \
        _Pragma("unroll")                                                                        \
        for (int f = 0; f < 2; f++)                                                              \
            _Pragma("unroll")                                                                    \
            for (int nt = 2; nt < 4; nt++) {                                                     \
                float e0 = __builtin_amdgcn_exp2f(sv[f][nt][0]);                                 \
                float e1 = __builtin_amdgcn_exp2f(sv[f][nt][1]);                                 \
                float e2 = __builtin_amdgcn_exp2f(sv[f][nt][2]);                                 \
                float e3 = __builtin_amdgcn_exp2f(sv[f][nt][3]);                                 \
                if (f == 0) lsum0 += (e0 + e1) + (e2 + e3); else lsum1 += (e0 + e1) + (e2 + e3); \
                u32x2 pk = {pack_bf2(e0, e1), pack_bf2(e2, e3)};                                 \
                *(u32x2*)(Pw + (f * 16 + qi) * 64 + ((2 * nt + (g >> 1)) ^ swz) * 8 + (g & 1) * 4) = pk; \
            }                                                                                    \
        {                                                                                        \
            bf16x8 bp0 = *(const bf16x8*)(Pw + qi * 64 + ((4 + g) ^ swz) * 8);                   \
            bf16x8 bp1 = *(const bf16x8*)(Pw + (16 + qi) * 64 + ((4 + g) ^ swz) * 8);            \
            _Pragma("unroll")                                                                    \
            for (int nt = 0; nt < 4; nt++) {                                                     \
                bf16x8 av = *(const bf16x8*)(vsp + (nt * 16 + qi) * 64 + ((4 + g) ^ swz) * 8);   \
                od[0][nt] = __builtin_amdgcn_mfma_f32_16x16x32_bf16(av, bp0, od[0][nt], 0, 0, 0); \
                od[1][nt] = __builtin_amdgcn_mfma_f32_16x16x32_bf16(av, bp1, od[1][nt], 0, 0, 0); \
            }                                                                                    \
        }                                                                                        \
        kg0 += 4096; kg1 += 4096; vg0 += 64; vg1 += 64;                                          \
    }

    for (int kt = 0; kt < 16; kt += 2) {
        ATTN_STEP(kt,     Ks[0], Vs[0], Ks[1], Vs[1]);
        ATTN_STEP(kt + 1, Ks[1], Vs[1], Ks[0], Vs[0]);
    }
    #undef ATTN_STEP

    lsum0 += __shfl_xor(lsum0, 16, 64);
    lsum0 += __shfl_xor(lsum0, 32, 64);
    lsum1 += __shfl_xor(lsum1, 16, 64);
    lsum1 += __shfl_xor(lsum1, 32, 64);
    // partial epilogue: OP[bh][q][d] bf16 (un-normalized), LS[half][bh][q] f32
    u16* OPh = half ? OP1 : OP0;
    const size_t pbase = (size_t)bh * 2048;
    #pragma unroll
    for (int f = 0; f < 2; f++) {
        int q = q0 + w * 32 + f * 16 + qi;
        u16* op = OPh + (pbase + q) * 64 + g * 4;
        #pragma unroll
        for (int nt = 0; nt < 4; nt++) {
            u16x4 o;
            o.x = f2bf(od[f][nt][0]); o.y = f2bf(od[f][nt][1]);
            o.z = f2bf(od[f][nt][2]); o.w = f2bf(od[f][nt][3]);
            *(u16x4*)(op + nt * 16) = o;
        }
        if (g == 0) LS[(size_t)half * 65536 + pbase + q] = (f == 0) ? lsum0 : lsum1;
    }
}

// ---------------------------------------------------------------- split-K reduce -> CTX bf16
__global__ __launch_bounds__(256) void k_red(const u16* __restrict__ OP0, const u16* __restrict__ OP1,
                                             const float* __restrict__ LS, u16* __restrict__ CTX) {
    int i4 = blockIdx.x * 256 + threadIdx.x;       // 1,048,576 threads, 4 elems each
    int e = i4 * 4;
    int m = e >> 10, col = e & 1023;
    int hh = col >> 6, d = col & 63;
    int b = m >> 11, q = m & 2047;
    size_t r = (size_t)(b * 16 + hh) * 2048 + q;
    u16x4 a0 = *(const u16x4*)(OP0 + r * 64 + d);
    u16x4 a1 = *(const u16x4*)(OP1 + r * 64 + d);
    float inv = 1.0f / (LS[r] + LS[65536 + r]);
    u16x4 o;
    o.x = f2bf((bf2f(a0.x) + bf2f(a1.x)) * inv);
    o.y = f2bf((bf2f(a0.y) + bf2f(a1.y)) * inv);
    o.z = f2bf((bf2f(a0.z) + bf2f(a1.z)) * inv);
    o.w = f2bf((bf2f(a0.w) + bf2f(a1.w)) * inv);
    *(u16x4*)(CTX + (size_t)m * 1024 + col) = o;
}

// ---------------------------------------------------------------- out GEMM + bias + residual -> fp32
__global__ __launch_bounds__(256) void k_out(const u16* __restrict__ CTX, const u16* __restrict__ Wo,
                                             const float* __restrict__ bout, const float* __restrict__ X,
                                             float* __restrict__ OUT) {
    __shared__ __align__(16) u16 As[128 * 64], Bs[128 * 64];
    f32x4 acc[4][4];
    const int m0 = blockIdx.y * 128, n0 = blockIdx.x * 128;
    gemm_bt_tile(CTX, Wo, m0, n0, As, Bs, acc);
    const int lane = threadIdx.x & 63, wid = threadIdx.x >> 6;
    const int wr = (wid >> 1) * 64, wc = (wid & 1) * 64;
    #pragma unroll
    for (int mi = 0; mi < 4; mi++)
        #pragma unroll
        for (int ni = 0; ni < 4; ni++)
            #pragma unroll
            for (int i = 0; i < 4; i++) {
                size_t m = m0 + wr + mi * 16 + ((lane >> 4) * 4 + i);
                int n = n0 + wc + ni * 16 + (lane & 15);
                OUT[m * 1024 + n] = acc[mi][ni][i] + bout[n] + X[m * 1024 + n];
            }
}

// ---------------------------------------------------------------- launch
extern "C" void kernel_launch(void* const* d_in, const int* in_sizes, int n_in,
                              void* d_out, int out_size, void* d_ws, size_t ws_size,
                              hipStream_t stream) {
    const float* X    = (const float*)d_in[0];
    const float* gam  = (const float*)d_in[1];
    const float* bet  = (const float*)d_in[2];
    const float* Wqkv = (const float*)d_in[3];
    const float* bqkv = (const float*)d_in[4];
    const float* Wout = (const float*)d_in[5];
    const float* bout = (const float*)d_in[6];
    float* OUT = (float*)d_out;

    u16* XN  = (u16*)d_ws;                       // dead after k_qkv -> reused as OP0
    u16* Q   = XN  + (size_t)4 * 1024 * 1024;
    u16* K   = Q   + (size_t)4 * 1024 * 1024;
    u16* Vt  = K   + (size_t)4 * 1024 * 1024;    // [bh,d,s] — written directly by k_qkv
    u16* CTX = Vt  + (size_t)4 * 1024 * 1024;
    u16* Wq  = CTX + (size_t)4 * 1024 * 1024;    // dead after k_qkv -> reused as LS
    u16* Wo  = Wq  + (size_t)3 * 1024 * 1024;
    u16* OP0 = XN;                               // 32*2048*64 u16 = exactly 4M u16
    u16* OP1 = Wo  + (size_t)1024 * 1024;        // +8 MB new space (ws total 56 MB)
    float* LS = (float*)Wq;                      // 2*32*2048 f32 = 512 KB (inside dead Wq)

    k_pre<<<8192, 256, 0, stream>>>(X, gam, bet, XN, Wqkv, Wq, Wout, Wo);
    k_qkv<<<dim3(24, 32), 256, 0, stream>>>(XN, Wq, bqkv, Q, K, Vt);
    k_attn<<<1024, 256, 0, stream>>>(Q, K, Vt, OP0, OP1, LS);
    k_red<<<4096, 256, 0, stream>>>(OP0, OP1, LS, CTX);
    k_out<<<dim3(8, 32), 256, 0, stream>>>(CTX, Wo, bout, X, OUT);
}

// Round 12
// 198.533 us; speedup vs baseline: 1.0673x; 1.0673x over previous
//
#include <hip/hip_runtime.h>
#include <stdint.h>

typedef unsigned short u16;
typedef __attribute__((ext_vector_type(8))) short bf16x8;   // 8 bf16 = 4 VGPRs (MFMA A/B frag)
typedef __attribute__((ext_vector_type(4))) float f32x4;    // MFMA C/D frag
typedef __attribute__((ext_vector_type(4))) unsigned int u32x4;
typedef __attribute__((ext_vector_type(2))) unsigned int u32x2;
typedef __attribute__((ext_vector_type(4))) unsigned short u16x4;

#define QSCALE 0.18033688011112042f   // 0.125 * log2(e): softmax scale folded into Q, exp via exp2

typedef __attribute__((address_space(1))) const void gvoid;
typedef __attribute__((address_space(3))) void svoid;

__device__ __forceinline__ void cp16(const u16* g, u16* l) {
    // async global->LDS, 16B/lane; LDS dst = wave-uniform base + lane*16
    __builtin_amdgcn_global_load_lds((gvoid*)g, (svoid*)l, 16, 0, 0);
}

__device__ __forceinline__ u16 f2bf(float f) {
    uint32_t u = __float_as_uint(f);
    u += 0x7fff + ((u >> 16) & 1);   // round-to-nearest-even
    return (u16)(u >> 16);
}

// pack bf16(lo), bf16(hi) into one u32: round-half-up — 2 adds + 1 perm per 2 elems
__device__ __forceinline__ uint32_t pack_bf2(float lo, float hi) {
    uint32_t a = __float_as_uint(lo) + 0x8000u;
    uint32_t b = __float_as_uint(hi) + 0x8000u;
    return __builtin_amdgcn_perm(b, a, 0x07060302);
}

// ---------------------------------------------------------------- fused pre-pass:
// blocks [0,4096): LayerNorm token t -> XN bf16; blocks [4096,8192): weight fp32->bf16 cast
__global__ __launch_bounds__(256) void k_pre(const float* __restrict__ X,
                                             const float* __restrict__ gam,
                                             const float* __restrict__ bet,
                                             u16* __restrict__ XN,
                                             const float* __restrict__ Wqkv, u16* __restrict__ Wq,
                                             const float* __restrict__ Wout, u16* __restrict__ Wo) {
    __shared__ float red[8];
    const int bid = blockIdx.x;
    if (bid < 4096) {
        int t = bid;
        const float4* xp = (const float4*)(X + (size_t)t * 1024);
        float4 x = xp[threadIdx.x];
        float s  = x.x + x.y + x.z + x.w;
        float s2 = x.x*x.x + x.y*x.y + x.z*x.z + x.w*x.w;
        #pragma unroll
        for (int off = 1; off < 64; off <<= 1) {
            s  += __shfl_xor(s,  off, 64);
            s2 += __shfl_xor(s2, off, 64);
        }
        int lane = threadIdx.x & 63, w = threadIdx.x >> 6;
        if (lane == 0) { red[w] = s; red[w + 4] = s2; }
        __syncthreads();
        s  = red[0] + red[1] + red[2] + red[3];
        s2 = red[4] + red[5] + red[6] + red[7];
        float mu  = s * (1.0f / 1024.0f);
        float var = s2 * (1.0f / 1024.0f) - mu * mu;
        float rin = rsqrtf(var + 1e-5f);
        float4 g = ((const float4*)gam)[threadIdx.x];
        float4 b = ((const float4*)bet)[threadIdx.x];
        u16x4 o;
        o.x = f2bf((x.x - mu) * rin * g.x + b.x);
        o.y = f2bf((x.y - mu) * rin * g.y + b.y);
        o.z = f2bf((x.z - mu) * rin * g.z + b.z);
        o.w = f2bf((x.w - mu) * rin * g.w + b.w);
        *(u16x4*)(XN + (size_t)t * 1024 + threadIdx.x * 4) = o;
    } else {
        int i = (bid - 4096) * 256 + threadIdx.x;      // over 1048576 float4s total
        const float* src; u16* dst;
        if (i < 786432) { src = Wqkv; dst = Wq; }
        else            { i -= 786432; src = Wout; dst = Wo; }
        float4 v = ((const float4*)src)[i];
        u16x4 o;
        o.x = f2bf(v.x); o.y = f2bf(v.y); o.z = f2bf(v.z); o.w = f2bf(v.w);
        ((u16x4*)dst)[i] = o;
    }
}

// ---------------------------------------------------------------- shared GEMM mainloop
// m97-style + XOR-granule swizzle: LDS granule (row,cg) holds global col-granule cg^(row&7).
__device__ __forceinline__ void gemm_bt_tile(const u16* __restrict__ A, const u16* __restrict__ Bm,
                                             int m0, int n0, u16* As, u16* Bs, f32x4 acc[4][4]) {
    const int tid = threadIdx.x;
    const int lane = tid & 63;
    const int wv = tid >> 6;
    const int qi = lane & 15, g = lane >> 4, swz = qi & 7;
    const int wr = (wv >> 1) * 64, wc = (wv & 1) * 64;
    #pragma unroll
    for (int mi = 0; mi < 4; mi++)
        #pragma unroll
        for (int ni = 0; ni < 4; ni++) acc[mi][ni] = (f32x4){0.f, 0.f, 0.f, 0.f};

    const int row_in = tid >> 3;
    const int cs = (tid & 7) ^ (row_in & 7);       // swizzled source col-granule (i*32 preserves row&7)
    for (int k0 = 0; k0 < 1024; k0 += 64) {
        __syncthreads();
        #pragma unroll
        for (int i = 0; i < 4; i++) {
            int row = i * 32 + row_in;
            cp16(A  + (size_t)(m0 + row) * 1024 + k0 + cs * 8, As + (i * 256 + wv * 64) * 8);
            cp16(Bm + (size_t)(n0 + row) * 1024 + k0 + cs * 8, Bs + (i * 256 + wv * 64) * 8);
        }
        __syncthreads();
        #pragma unroll
        for (int ks = 0; ks < 2; ks++) {
            bf16x8 af[4], bf[4];
            #pragma unroll
            for (int mi = 0; mi < 4; mi++)
                af[mi] = *(const bf16x8*)(As + (wr + mi * 16 + qi) * 64 + ((ks * 4 + g) ^ swz) * 8);
            #pragma unroll
            for (int ni = 0; ni < 4; ni++)
                bf[ni] = *(const bf16x8*)(Bs + (wc + ni * 16 + qi) * 64 + ((ks * 4 + g) ^ swz) * 8);
            #pragma unroll
            for (int mi = 0; mi < 4; mi++)
                #pragma unroll
                for (int ni = 0; ni < 4; ni++)
                    acc[mi][ni] = __builtin_amdgcn_mfma_f32_16x16x32_bf16(af[mi], bf[ni], acc[mi][ni], 0, 0, 0);
        }
    }
}

// ---------------------------------------------------------------- QKV GEMM + bias + scatter
__global__ __launch_bounds__(256) void k_qkv(const u16* __restrict__ XN, const u16* __restrict__ Wq,
                                             const float* __restrict__ bqkv,
                                             u16* __restrict__ Q, u16* __restrict__ K,
                                             u16* __restrict__ Vt) {
    __shared__ __align__(16) u16 SMEM[17408];      // union: As+Bs (16384) | 4 x T(64x68=4352)
    u16* As = SMEM;
    u16* Bs = SMEM + 8192;
    f32x4 acc[4][4];
    const int m0 = blockIdx.y * 128, n0 = blockIdx.x * 128;
    gemm_bt_tile(XN, Wq, m0, n0, As, Bs, acc);
    const int lane = threadIdx.x & 63, wid = threadIdx.x >> 6;
    const int g = lane >> 4, qi = lane & 15;
    const int wr = (wid >> 1) * 64, wc = (wid & 1) * 64;
    if (n0 < 2048) {
        const int which = n0 >> 10;                // 0 = Q, 1 = K (block-uniform)
        u16* base = which ? K : Q;
        const float scale = which ? 1.0f : QSCALE;
        #pragma unroll
        for (int mi = 0; mi < 4; mi++)
            #pragma unroll
            for (int ni = 0; ni < 4; ni++)
                #pragma unroll
                for (int i = 0; i < 4; i++) {
                    int m = m0 + wr + mi * 16 + (g * 4 + i);
                    int n = n0 + wc + ni * 16 + qi;
                    float v = (acc[mi][ni][i] + bqkv[n]) * scale;
                    int b = m >> 11, s = m & 2047;
                    int hh = (n >> 6) & 15, d = n & 63;
                    base[((size_t)(b * 16 + hh) * 2048 + s) * 64 + d] = f2bf(v);
                }
    } else {
        __syncthreads();                           // all waves done reading As/Bs
        u16* Tw = SMEM + wid * 4352;               // per-wave 64x68 (stride 68: 8B-aligned rows)
        #pragma unroll
        for (int mi = 0; mi < 4; mi++)
            #pragma unroll
            for (int ni = 0; ni < 4; ni++) {
                int n = n0 + wc + ni * 16 + qi;
                float bq = bqkv[n];
                u16x4 pk;
                pk.x = f2bf(acc[mi][ni][0] + bq);
                pk.y = f2bf(acc[mi][ni][1] + bq);
                pk.z = f2bf(acc[mi][ni][2] + bq);
                pk.w = f2bf(acc[mi][ni][3] + bq);
                *(u16x4*)(Tw + (ni * 16 + qi) * 68 + mi * 16 + g * 4) = pk;
            }
        const int head = (n0 + wc - 2048) >> 6;
        const int b = m0 >> 11;
        const int s0 = (m0 + wr) & 2047;           // s within the batch (R7 fix)
        u16* vrow = Vt + (size_t)(b * 16 + head) * 64 * 2048 + s0 + qi * 4;
        #pragma unroll
        for (int dd = 0; dd < 16; dd++) {
            int d = dd * 4 + g;
            u16x4 val = *(const u16x4*)(Tw + d * 68 + qi * 4);
            *(u16x4*)(vrow + (size_t)d * 2048) = val;
        }
    }
}

// ---------------------------------------------------------------- attention (R9 config — empirical optimum)
// q-tile 128 via 512-thread blocks (8 waves x 16 q), F=1. R10 (F=2, 4 waves) and R11
// (split-K) both regressed: the F=2 traffic cut costs the wave count (4096/F total waves)
// needed to keep the LDS pipe fed, and residency never recovered (occ stuck 18%).
// This config: 16 waves/CU, ~20 KB LDS traffic/wave/kt == LDS-BW model ~= 54 µs.
__global__ __launch_bounds__(512) void k_attn(const u16* __restrict__ Q, const u16* __restrict__ K,
                                              const u16* __restrict__ Vt, u16* __restrict__ CTX) {
    __shared__ __align__(16) u16 Ks[2][64 * 64];   // elem(key r, d c) at r*64 + ((c>>3)^(r&7))*8 + (c&7)
    __shared__ __align__(16) u16 Vs[2][64 * 64];   // elem(d r, key c) same swizzle
    __shared__ __align__(16) u16 Ps[8][16 * 64];   // per-wave, elem(q r, key c) same swizzle
    const int id = blockIdx.x;
    const int bh = (id & 7) * 4 + ((id >> 3) & 3); // id%8 constant per bh -> same XCD
    const int q0 = (id >> 5) * 128;
    const int lane = threadIdx.x & 63, w = threadIdx.x >> 6;   // w in 0..7
    const int g = lane >> 4, qi = lane & 15, swz = qi & 7;
    const u16* Qp = Q  + (size_t)bh * (2048 * 64);
    const u16* Kp = K  + (size_t)bh * (2048 * 64);
    const u16* Vp = Vt + (size_t)bh * (64 * 2048);
    u16* Pw = Ps[w];

    // staging: 8 waves x 64 lanes x 16B = one full 64x64 bf16 tile per cp16
    const int r0 = w * 8 + (lane >> 3);            // tile row 0..63
    const int cs = (lane & 7) ^ (r0 & 7);          // swizzled col-granule
    const u16* kg0 = Kp + (size_t)r0 * 64 + cs * 8;
    const u16* vg0 = Vp + (size_t)r0 * 2048 + cs * 8;

    bf16x8 bq[2];
    {
        const u16* qb = Qp + (size_t)(q0 + w * 16 + qi) * 64 + g * 8;
        bq[0] = *(const bf16x8*)(qb);
        bq[1] = *(const bf16x8*)(qb + 32);
    }
    float lsumA = 0.f, lsumB = 0.f;
    f32x4 od[4];
    #pragma unroll
    for (int nt = 0; nt < 4; nt++) od[nt] = (f32x4){0.f, 0.f, 0.f, 0.f};

    // preload tile 0 -> buf 0
    cp16(kg0, Ks[0] + w * 512);
    cp16(vg0, Vs[0] + w * 512);

    #define ATTN_STEP(KT, CKS, CVS, PKS, PVS)                                                    \
    {                                                                                            \
        const int kt_ = (KT);                                                                    \
        __syncthreads();                                                                         \
        if (kt_ < 31) {                                                                          \
            cp16(kg0 + 4096, (PKS) + w * 512);     /* next K tile: +64 keys * 64 d */            \
            cp16(vg0 + 64,   (PVS) + w * 512);     /* next V tile: +64 keys (minor dim) */       \
        }                                                                                        \
        const u16* ksp = (CKS);                                                                  \
        const u16* vsp = (CVS);                                                                  \
        f32x4 sv[4];                                                                             \
        _Pragma("unroll")                                                                        \
        for (int nt = 0; nt < 4; nt++) sv[nt] = (f32x4){0.f, 0.f, 0.f, 0.f};                     \
        _Pragma("unroll")                                                                        \
        for (int ks = 0; ks < 2; ks++)                                                           \
            _Pragma("unroll")                                                                    \
            for (int nt = 0; nt < 4; nt++) {                                                     \
                bf16x8 ak = *(const bf16x8*)(ksp + (nt * 16 + qi) * 64 + ((ks * 4 + g) ^ swz) * 8); \
                sv[nt] = __builtin_amdgcn_mfma_f32_16x16x32_bf16(ak, bq[ks], sv[nt], 0, 0, 0);   \
            }                                                                                    \
        _Pragma("unroll")                                                                        \
        for (int nt = 0; nt < 2; nt++) {                                                         \
            float e0 = __builtin_amdgcn_exp2f(sv[nt][0]);                                        \
            float e1 = __builtin_amdgcn_exp2f(sv[nt][1]);                                        \
            float e2 = __builtin_amdgcn_exp2f(sv[nt][2]);                                        \
            float e3 = __builtin_amdgcn_exp2f(sv[nt][3]);                                        \
            lsumA += e0 + e1; lsumB += e2 + e3;                                                  \
            u32x2 pk = {pack_bf2(e0, e1), pack_bf2(e2, e3)};                                     \
            *(u32x2*)(Pw + qi * 64 + ((2 * nt + (g >> 1)) ^ swz) * 8 + (g & 1) * 4) = pk;        \
        }                                                                                        \
        {                                                                                        \
            bf16x8 bp = *(const bf16x8*)(Pw + qi * 64 + ((0 * 4 + g) ^ swz) * 8);                \
            _Pragma("unroll")                                                                    \
            for (int nt = 0; nt < 4; nt++) {                                                     \
                bf16x8 av = *(const bf16x8*)(vsp + (nt * 16 + qi) * 64 + ((0 * 4 + g) ^ swz) * 8); \
                od[nt] = __builtin_amdgcn_mfma_f32_16x16x32_bf16(av, bp, od[nt], 0, 0, 0);       \
            }                                                                                    \
        }                                                                                        \
        _Pragma("unroll")                                                                        \
        for (int nt = 2; nt < 4; nt++) {                                                         \
            float e0 = __builtin_amdgcn_exp2f(sv[nt][0]);                                        \
            float e1 = __builtin_amdgcn_exp2f(sv[nt][1]);                                        \
            float e2 = __builtin_amdgcn_exp2f(sv[nt][2]);                                        \
            float e3 = __builtin_amdgcn_exp2f(sv[nt][3]);                                        \
            lsumA += e0 + e1; lsumB += e2 + e3;                                                  \
            u32x2 pk = {pack_bf2(e0, e1), pack_bf2(e2, e3)};                                     \
            *(u32x2*)(Pw + qi * 64 + ((2 * nt + (g >> 1)) ^ swz) * 8 + (g & 1) * 4) = pk;        \
        }                                                                                        \
        {                                                                                        \
            bf16x8 bp = *(const bf16x8*)(Pw + qi * 64 + ((1 * 4 + g) ^ swz) * 8);                \
            _Pragma("unroll")                                                                    \
            for (int nt = 0; nt < 4; nt++) {                                                     \
                bf16x8 av = *(const bf16x8*)(vsp + (nt * 16 + qi) * 64 + ((1 * 4 + g) ^ swz) * 8); \
                od[nt] = __builtin_amdgcn_mfma_f32_16x16x32_bf16(av, bp, od[nt], 0, 0, 0);       \
            }                                                                                    \
        }                                                                                        \
        kg0 += 64 * 64; vg0 += 64;                                                               \
    }

    for (int kt = 0; kt < 32; kt += 2) {
        ATTN_STEP(kt,     Ks[0], Vs[0], Ks[1], Vs[1]);
        ATTN_STEP(kt + 1, Ks[1], Vs[1], Ks[0], Vs[0]);
    }
    #undef ATTN_STEP

    float lsum = lsumA + lsumB;
    lsum += __shfl_xor(lsum, 16, 64);
    lsum += __shfl_xor(lsum, 32, 64);
    float inv = 1.0f / lsum;
    const int b = bh >> 4, hh = bh & 15;
    size_t m = (size_t)b * 2048 + q0 + w * 16 + qi;
    u16* cp = CTX + m * 1024 + hh * 64 + g * 4;
    #pragma unroll
    for (int nt = 0; nt < 4; nt++) {
        u16x4 o;
        o.x = f2bf(od[nt][0] * inv); o.y = f2bf(od[nt][1] * inv);
        o.z = f2bf(od[nt][2] * inv); o.w = f2bf(od[nt][3] * inv);
        *(u16x4*)(cp + nt * 16) = o;
    }
}

// ---------------------------------------------------------------- out GEMM + bias + residual -> fp32
__global__ __launch_bounds__(256) void k_out(const u16* __restrict__ CTX, const u16* __restrict__ Wo,
                                             const float* __restrict__ bout, const float* __restrict__ X,
                                             float* __restrict__ OUT) {
    __shared__ __align__(16) u16 As[128 * 64], Bs[128 * 64];
    f32x4 acc[4][4];
    const int m0 = blockIdx.y * 128, n0 = blockIdx.x * 128;
    gemm_bt_tile(CTX, Wo, m0, n0, As, Bs, acc);
    const int lane = threadIdx.x & 63, wid = threadIdx.x >> 6;
    const int wr = (wid >> 1) * 64, wc = (wid & 1) * 64;
    #pragma unroll
    for (int mi = 0; mi < 4; mi++)
        #pragma unroll
        for (int ni = 0; ni < 4; ni++)
            #pragma unroll
            for (int i = 0; i < 4; i++) {
                size_t m = m0 + wr + mi * 16 + ((lane >> 4) * 4 + i);
                int n = n0 + wc + ni * 16 + (lane & 15);
                OUT[m * 1024 + n] = acc[mi][ni][i] + bout[n] + X[m * 1024 + n];
            }
}

// ---------------------------------------------------------------- launch
extern "C" void kernel_launch(void* const* d_in, const int* in_sizes, int n_in,
                              void* d_out, int out_size, void* d_ws, size_t ws_size,
                              hipStream_t stream) {
    const float* X    = (const float*)d_in[0];
    const float* gam  = (const float*)d_in[1];
    const float* bet  = (const float*)d_in[2];
    const float* Wqkv = (const float*)d_in[3];
    const float* bqkv = (const float*)d_in[4];
    const float* Wout = (const float*)d_in[5];
    const float* bout = (const float*)d_in[6];
    float* OUT = (float*)d_out;

    u16* XN  = (u16*)d_ws;
    u16* Q   = XN  + (size_t)4 * 1024 * 1024;
    u16* K   = Q   + (size_t)4 * 1024 * 1024;
    u16* Vt  = K   + (size_t)4 * 1024 * 1024;    // [bh,d,s] — written directly by k_qkv
    u16* CTX = Vt  + (size_t)4 * 1024 * 1024;
    u16* Wq  = CTX + (size_t)4 * 1024 * 1024;
    u16* Wo  = Wq  + (size_t)3 * 1024 * 1024;

    k_pre<<<8192, 256, 0, stream>>>(X, gam, bet, XN, Wqkv, Wq, Wout, Wo);
    k_qkv<<<dim3(24, 32), 256, 0, stream>>>(XN, Wq, bqkv, Q, K, Vt);
    k_attn<<<512, 512, 0, stream>>>(Q, K, Vt, CTX);
    k_out<<<dim3(8, 32), 256, 0, stream>>>(CTX, Wo, bout, X, OUT);
}